// Round 1
// baseline (223.241 us; speedup 1.0000x reference)
//
#include <hip/hip_runtime.h>
#include <hip/hip_bf16.h>

// LinMHA: out = q @ Wc[b] + b_o, Wc[b] = Wq^T @ blockdiag(SCALE^2 * (K'^T V')_heads) @ Wo^T
// K' = k@Wk^T, V' = v@Wv^T.  B=4, S=8192, C=512, H=8, DK=64.

typedef __attribute__((ext_vector_type(4))) float f32x4;
typedef __attribute__((ext_vector_type(8))) short short8;

#define DEVI __device__ __forceinline__

DEVI unsigned short f2bf(float f) {
  unsigned int u = __builtin_bit_cast(unsigned int, f);
  u += 0x7fffu + ((u >> 16) & 1u);   // RNE
  return (unsigned short)(u >> 16);
}
DEVI float bf2f(unsigned short s) {
  unsigned int u = ((unsigned int)s) << 16;
  return __builtin_bit_cast(float, u);
}

// ---------------- K1: X' = x @ W^T  -> bf16 [32768][512] ----------------
// TN GEMM: A = x rows (M,K-contig), B = W rows (N,K-contig). 128x128 tile, 4 waves.
__global__ __launch_bounds__(256) void proj_kernel(const float* __restrict__ x,
                                                   const float* __restrict__ W,
                                                   unsigned short* __restrict__ out) {
  __shared__ __align__(16) unsigned short Ab[128 * 48];  // [row][k] pad 48 (16B-aligned rows)
  __shared__ __align__(16) unsigned short Bb[128 * 48];
  const int t = threadIdx.x;
  const int m0 = blockIdx.x * 128;
  const int n0 = blockIdx.y * 128;
  const int lane = t & 63, w = t >> 6;
  const int wm = (w >> 1) * 64, wn = (w & 1) * 64;
  const int fr = lane & 15, fg = lane >> 4;
  const int sr = t >> 2;         // 0..63
  const int sk = (t & 3) * 8;    // 0,8,16,24
  f32x4 acc[4][4] = {};

  for (int step = 0; step < 16; ++step) {
    const int k0 = step * 32;
#pragma unroll
    for (int half = 0; half < 2; ++half) {
      const int row = sr + half * 64;
      const float* pa = x + (size_t)(m0 + row) * 512 + k0 + sk;
      const float* pb = W + (size_t)(n0 + row) * 512 + k0 + sk;
      f32x4 a0 = *(const f32x4*)pa;
      f32x4 a1 = *(const f32x4*)(pa + 4);
      f32x4 b0 = *(const f32x4*)pb;
      f32x4 b1 = *(const f32x4*)(pb + 4);
      short8 pa8, pb8;
#pragma unroll
      for (int i = 0; i < 4; ++i) {
        pa8[i] = (short)f2bf(a0[i]);
        pa8[i + 4] = (short)f2bf(a1[i]);
        pb8[i] = (short)f2bf(b0[i]);
        pb8[i + 4] = (short)f2bf(b1[i]);
      }
      *(short8*)&Ab[row * 48 + sk] = pa8;
      *(short8*)&Bb[row * 48 + sk] = pb8;
    }
    __syncthreads();
    short8 afr[4], bfr[4];
#pragma unroll
    for (int i = 0; i < 4; ++i) {
      afr[i] = *(const short8*)&Ab[(wm + i * 16 + fr) * 48 + fg * 8];
      bfr[i] = *(const short8*)&Bb[(wn + i * 16 + fr) * 48 + fg * 8];
    }
#pragma unroll
    for (int i = 0; i < 4; ++i)
#pragma unroll
      for (int j = 0; j < 4; ++j)
        acc[i][j] = __builtin_amdgcn_mfma_f32_16x16x32_bf16(afr[i], bfr[j], acc[i][j], 0, 0, 0);
    __syncthreads();
  }
#pragma unroll
  for (int i = 0; i < 4; ++i)
#pragma unroll
    for (int j = 0; j < 4; ++j)
#pragma unroll
      for (int r = 0; r < 4; ++r) {
        const int row = m0 + wm + i * 16 + fg * 4 + r;   // C/D: row=(lane>>4)*4+reg
        const int col = n0 + wn + j * 16 + fr;           //      col=lane&15
        out[(size_t)row * 512 + col] = f2bf(acc[i][j][r]);
      }
}

// ---------------- K2: G partials = sum_s K'[s,hd]*V'[s,he] over s-chunks ----------------
// grid (16 s-chunks, 32 bh). fp32 VALU outer-product, 4x4 acc per thread.
__global__ __launch_bounds__(256) void gpart_kernel(const unsigned short* __restrict__ Kp,
                                                    const unsigned short* __restrict__ Vp,
                                                    float* __restrict__ Gpart) {
  __shared__ float Kl[16][64];
  __shared__ float Vl[16][64];
  const int t = threadIdx.x;
  const int chunk = blockIdx.x;   // 16
  const int bh = blockIdx.y;      // 32
  const int b = bh >> 3, h = bh & 7;
  const int s0 = chunk * 512;
  const int d0 = (t >> 4) * 4;
  const int e0 = (t & 15) * 4;
  const int isV = t >> 7;                  // waves 0,1 stage K; waves 2,3 stage V
  const int rr = (t & 127) >> 3;           // 0..15
  const int cc = (t & 7) * 8;              // 0..56
  const unsigned short* src = (isV ? Vp : Kp) + (size_t)(b * 8192 + s0) * 512 + h * 64 + cc;
  float* dl = (isV ? &Vl[0][0] : &Kl[0][0]) + rr * 64 + cc;
  float acc[4][4] = {};
  for (int ss = 0; ss < 512; ss += 16) {
    short8 u = *(const short8*)(src + (size_t)(ss + rr) * 512);
#pragma unroll
    for (int i = 0; i < 8; ++i) dl[i] = bf2f((unsigned short)u[i]);
    __syncthreads();
#pragma unroll
    for (int qq = 0; qq < 16; ++qq) {
      f32x4 kv = *(const f32x4*)&Kl[qq][d0];
      f32x4 vv = *(const f32x4*)&Vl[qq][e0];
#pragma unroll
      for (int i = 0; i < 4; ++i)
#pragma unroll
        for (int j = 0; j < 4; ++j)
          acc[i][j] += kv[i] * vv[j];
    }
    __syncthreads();
  }
  float* gp = Gpart + ((size_t)chunk * 32 + bh) * 4096;
#pragma unroll
  for (int i = 0; i < 4; ++i)
#pragma unroll
    for (int j = 0; j < 4; ++j)
      gp[(d0 + i) * 64 + (e0 + j)] = acc[i][j];
}

// ---------------- K2b: Gsum = SCALE^2 * sum_chunks Gpart ----------------
__global__ __launch_bounds__(256) void gsum_kernel(const float* __restrict__ Gpart,
                                                   float* __restrict__ Gsum) {
  const int idx = blockIdx.x * 256 + threadIdx.x;  // 131072 total
  float s = 0.f;
#pragma unroll
  for (int c = 0; c < 16; ++c) s += Gpart[(size_t)c * 131072 + idx];
  Gsum[idx] = s * (1.0f / 64.0f);  // SCALE^2 = 1/dk
}

// ---------------- K3a: T3[b][c][h*64+e] = sum_d Wq[h*64+d][c] * G[b,h,d,e] -> bf16 ----------------
__global__ __launch_bounds__(256) void t3_kernel(const float* __restrict__ Wq,
                                                 const float* __restrict__ Gsum,
                                                 unsigned short* __restrict__ T3) {
  __shared__ float Wl[64][64];  // [d][c]
  __shared__ float Gl[64][64];  // [d][e]
  const int t = threadIdx.x;
  const int c0 = blockIdx.x * 64;
  const int h = blockIdx.y;
  const int b = blockIdx.z;
  const int dd = t >> 2;
  const int c4 = (t & 3) * 16;
  const float* wp = Wq + (size_t)(h * 64 + dd) * 512 + c0 + c4;
  const float* gp = Gsum + (size_t)(b * 8 + h) * 4096 + dd * 64 + c4;
#pragma unroll
  for (int i = 0; i < 4; ++i) {
    *(f32x4*)&Wl[dd][c4 + i * 4] = *(const f32x4*)(wp + i * 4);
    *(f32x4*)&Gl[dd][c4 + i * 4] = *(const f32x4*)(gp + i * 4);
  }
  __syncthreads();
  const int cl0 = (t >> 4) * 4;
  const int e0 = (t & 15) * 4;
  float acc[4][4] = {};
  for (int d = 0; d < 64; ++d) {
    f32x4 wv = *(const f32x4*)&Wl[d][cl0];
    f32x4 gv = *(const f32x4*)&Gl[d][e0];
#pragma unroll
    for (int i = 0; i < 4; ++i)
#pragma unroll
      for (int j = 0; j < 4; ++j)
        acc[i][j] += wv[i] * gv[j];
  }
#pragma unroll
  for (int i = 0; i < 4; ++i)
#pragma unroll
    for (int j = 0; j < 4; ++j)
      T3[((size_t)b * 512 + c0 + cl0 + i) * 512 + h * 64 + e0 + j] = f2bf(acc[i][j]);
}

// ---------------- K3b: WcT[b][n][c] = sum_j Wo[n][j] * T3[b][c][j] -> bf16 (MFMA, 1 wave) ----------------
__global__ __launch_bounds__(64) void wc_kernel(const float* __restrict__ Wo,
                                                const unsigned short* __restrict__ T3,
                                                unsigned short* __restrict__ WcT) {
  __shared__ __align__(16) unsigned short Ao[64 * 48];
  __shared__ __align__(16) unsigned short Bo[64 * 48];
  const int t = threadIdx.x;  // 0..63
  const int n0 = blockIdx.x * 64;
  const int c0 = blockIdx.y * 64;
  const int b = blockIdx.z;
  const int fr = t & 15, fg = t >> 4;
  f32x4 acc[4][4] = {};
  for (int step = 0; step < 16; ++step) {
    const int k0 = step * 32;
    const float* pa = Wo + (size_t)(n0 + t) * 512 + k0;
    unsigned short tmp[32];
#pragma unroll
    for (int i = 0; i < 8; ++i) {
      f32x4 vv = *(const f32x4*)(pa + i * 4);
#pragma unroll
      for (int j = 0; j < 4; ++j) tmp[i * 4 + j] = f2bf(vv[j]);
    }
#pragma unroll
    for (int i = 0; i < 4; ++i) *(short8*)&Ao[t * 48 + i * 8] = *(const short8*)&tmp[i * 8];
    const unsigned short* pb = T3 + ((size_t)b * 512 + c0 + t) * 512 + k0;
#pragma unroll
    for (int i = 0; i < 4; ++i) *(short8*)&Bo[t * 48 + i * 8] = *(const short8*)(pb + i * 8);
    __syncthreads();
    short8 afr[4], bfr[4];
#pragma unroll
    for (int i = 0; i < 4; ++i) {
      afr[i] = *(const short8*)&Ao[(i * 16 + fr) * 48 + fg * 8];
      bfr[i] = *(const short8*)&Bo[(i * 16 + fr) * 48 + fg * 8];
    }
#pragma unroll
    for (int i = 0; i < 4; ++i)
#pragma unroll
      for (int j = 0; j < 4; ++j)
        acc[i][j] = __builtin_amdgcn_mfma_f32_16x16x32_bf16(afr[i], bfr[j], acc[i][j], 0, 0, 0);
    __syncthreads();
  }
#pragma unroll
  for (int i = 0; i < 4; ++i)
#pragma unroll
    for (int j = 0; j < 4; ++j)
#pragma unroll
      for (int r = 0; r < 4; ++r)
        WcT[((size_t)b * 512 + n0 + i * 16 + fg * 4 + r) * 512 + c0 + j * 16 + fr] =
            f2bf(acc[i][j][r]);
}

// ---------------- K4: Out = q @ Wc[b] + b_o -> f32 ----------------
__global__ __launch_bounds__(256) void out_kernel(const float* __restrict__ q,
                                                  const unsigned short* __restrict__ WcT,
                                                  const float* __restrict__ bo,
                                                  float* __restrict__ Out) {
  __shared__ __align__(16) unsigned short Ab[128 * 48];
  __shared__ __align__(16) unsigned short Bb[128 * 48];
  const int t = threadIdx.x;
  const int m0 = blockIdx.x * 128;
  const int n0 = blockIdx.y * 128;
  const unsigned short* Wc = WcT + ((size_t)(m0 >> 13)) * 512 * 512;  // batch = m0/8192
  const int lane = t & 63, w = t >> 6;
  const int wm = (w >> 1) * 64, wn = (w & 1) * 64;
  const int fr = lane & 15, fg = lane >> 4;
  const int sr = t >> 2;
  const int sk = (t & 3) * 8;
  f32x4 acc[4][4] = {};

  for (int step = 0; step < 16; ++step) {
    const int k0 = step * 32;
#pragma unroll
    for (int half = 0; half < 2; ++half) {
      const int row = sr + half * 64;
      const float* pa = q + (size_t)(m0 + row) * 512 + k0 + sk;
      f32x4 a0 = *(const f32x4*)pa;
      f32x4 a1 = *(const f32x4*)(pa + 4);
      short8 pa8;
#pragma unroll
      for (int i = 0; i < 4; ++i) {
        pa8[i] = (short)f2bf(a0[i]);
        pa8[i + 4] = (short)f2bf(a1[i]);
      }
      *(short8*)&Ab[row * 48 + sk] = pa8;
      *(short8*)&Bb[row * 48 + sk] =
          *(const short8*)(Wc + (size_t)(n0 + row) * 512 + k0 + sk);
    }
    __syncthreads();
    short8 afr[4], bfr[4];
#pragma unroll
    for (int i = 0; i < 4; ++i) {
      afr[i] = *(const short8*)&Ab[(wm + i * 16 + fr) * 48 + fg * 8];
      bfr[i] = *(const short8*)&Bb[(wn + i * 16 + fr) * 48 + fg * 8];
    }
#pragma unroll
    for (int i = 0; i < 4; ++i)
#pragma unroll
      for (int j = 0; j < 4; ++j)
        acc[i][j] = __builtin_amdgcn_mfma_f32_16x16x32_bf16(afr[i], bfr[j], acc[i][j], 0, 0, 0);
    __syncthreads();
  }
  float bias[4];
#pragma unroll
  for (int j = 0; j < 4; ++j) bias[j] = bo[n0 + wn + j * 16 + fr];
#pragma unroll
  for (int i = 0; i < 4; ++i)
#pragma unroll
    for (int j = 0; j < 4; ++j)
#pragma unroll
      for (int r = 0; r < 4; ++r) {
        const int row = m0 + wm + i * 16 + fg * 4 + r;
        const int col = n0 + wn + j * 16 + fr;
        Out[(size_t)row * 512 + col] = acc[i][j][r] + bias[j];
      }
}

extern "C" void kernel_launch(void* const* d_in, const int* in_sizes, int n_in,
                              void* d_out, int out_size, void* d_ws, size_t ws_size,
                              hipStream_t stream) {
  const float* q  = (const float*)d_in[0];
  const float* k  = (const float*)d_in[1];
  const float* v  = (const float*)d_in[2];
  const float* Wq = (const float*)d_in[3];
  const float* Wk = (const float*)d_in[4];
  const float* Wv = (const float*)d_in[5];
  const float* Wo = (const float*)d_in[6];
  const float* bo = (const float*)d_in[7];
  float* Out = (float*)d_out;

  // Scratch: K'/V' (bf16, 32MB each) live inside d_out (64MB) until K4 overwrites it.
  unsigned short* Kp = (unsigned short*)d_out;
  unsigned short* Vp = Kp + (size_t)16777216;
  char* ws = (char*)d_ws;
  float* Gpart        = (float*)ws;                          // 8 MB
  float* Gsum         = (float*)(ws + (size_t)8  * 1048576); // 0.5 MB
  unsigned short* T3  = (unsigned short*)(ws + (size_t)9  * 1048576); // 2 MB
  unsigned short* WcT = (unsigned short*)(ws + (size_t)11 * 1048576); // 2 MB

  proj_kernel<<<dim3(256, 4), dim3(256), 0, stream>>>(k, Wk, Kp);
  proj_kernel<<<dim3(256, 4), dim3(256), 0, stream>>>(v, Wv, Vp);
  gpart_kernel<<<dim3(16, 32), dim3(256), 0, stream>>>(Kp, Vp, Gpart);
  gsum_kernel<<<dim3(512), dim3(256), 0, stream>>>(Gpart, Gsum);
  t3_kernel<<<dim3(8, 8, 4), dim3(256), 0, stream>>>(Wq, Gsum, T3);
  wc_kernel<<<dim3(8, 8, 4), dim3(64), 0, stream>>>(Wo, T3, WcT);
  out_kernel<<<dim3(256, 4), dim3(256), 0, stream>>>(q, WcT, bo, Out);
}

// Round 2
// 217.839 us; speedup vs baseline: 1.0248x; 1.0248x over previous
//
#include <hip/hip_runtime.h>
#include <hip/hip_bf16.h>

// LinMHA: out = q @ Wc[b] + b_o, Wc[b] = Wq^T @ blockdiag(SCALE^2 * (K'^T V')_heads) @ Wo^T
// K' = k@Wk^T, V' = v@Wv^T.  B=4, S=8192, C=512, H=8, DK=64.

typedef __attribute__((ext_vector_type(4))) float f32x4;
typedef __attribute__((ext_vector_type(8))) short short8;

#define DEVI __device__ __forceinline__

DEVI unsigned short f2bf(float f) {
  unsigned int u = __builtin_bit_cast(unsigned int, f);
  u += 0x7fffu + ((u >> 16) & 1u);   // RNE
  return (unsigned short)(u >> 16);
}
DEVI float bf2f(unsigned short s) {
  unsigned int u = ((unsigned int)s) << 16;
  return __builtin_bit_cast(float, u);
}
DEVI short8 pack8(f32x4 a, f32x4 b) {
  short8 r;
#pragma unroll
  for (int i = 0; i < 4; ++i) { r[i] = (short)f2bf(a[i]); r[i + 4] = (short)f2bf(b[i]); }
  return r;
}

// ---------------- K1: fused dual projection X' = x @ W^T -> bf16 [32768][512] ----------------
// 128x128 tile, BK=32, 4 waves. 2-phase pipeline: double LDS buffer + register prefetch,
// one barrier per K-step. z=0: (k,Wk)->Kp, z=1: (v,Wv)->Vp.
__global__ __launch_bounds__(256, 3) void proj2_kernel(const float* __restrict__ kin,
                                                       const float* __restrict__ vin,
                                                       const float* __restrict__ Wk,
                                                       const float* __restrict__ Wv,
                                                       unsigned short* __restrict__ Kp) {
  __shared__ __align__(16) unsigned short Ab[2][128 * 40];  // row stride 40 shorts (80B)
  __shared__ __align__(16) unsigned short Bb[2][128 * 40];
  const int t = threadIdx.x;
  const int n0 = blockIdx.x * 128;
  const int m0 = blockIdx.y * 128;
  const int zsel = blockIdx.z;
  const float* x = zsel ? vin : kin;
  const float* W = zsel ? Wv : Wk;
  unsigned short* outp = Kp + (size_t)zsel * 16777216;

  const int lane = t & 63, w = t >> 6;
  const int wm = (w >> 1) * 64, wn = (w & 1) * 64;
  const int fr = lane & 15, fg = lane >> 4;
  const int sr = t >> 2;        // 0..63
  const int sk = (t & 3) * 8;   // 0,8,16,24

  const float* pAg = x + (size_t)(m0 + sr) * 512 + sk;
  const float* pBg = W + (size_t)(n0 + sr) * 512 + sk;

  f32x4 acc[4][4] = {};
  f32x4 a0, a1, a2, a3, b0, b1, b2, b3;

  a0 = *(const f32x4*)(pAg);         a1 = *(const f32x4*)(pAg + 4);
  a2 = *(const f32x4*)(pAg + 32768); a3 = *(const f32x4*)(pAg + 32772);
  b0 = *(const f32x4*)(pBg);         b1 = *(const f32x4*)(pBg + 4);
  b2 = *(const f32x4*)(pBg + 32768); b3 = *(const f32x4*)(pBg + 32772);
  *(short8*)&Ab[0][sr * 40 + sk] = pack8(a0, a1);
  *(short8*)&Ab[0][(sr + 64) * 40 + sk] = pack8(a2, a3);
  *(short8*)&Bb[0][sr * 40 + sk] = pack8(b0, b1);
  *(short8*)&Bb[0][(sr + 64) * 40 + sk] = pack8(b2, b3);
  __syncthreads();

  for (int step = 0; step < 16; ++step) {
    const int cur = step & 1;
    if (step < 15) {  // issue next-step globals early (overlap with ds_read+MFMA)
      const int k1 = (step + 1) * 32;
      a0 = *(const f32x4*)(pAg + k1);         a1 = *(const f32x4*)(pAg + k1 + 4);
      a2 = *(const f32x4*)(pAg + k1 + 32768); a3 = *(const f32x4*)(pAg + k1 + 32772);
      b0 = *(const f32x4*)(pBg + k1);         b1 = *(const f32x4*)(pBg + k1 + 4);
      b2 = *(const f32x4*)(pBg + k1 + 32768); b3 = *(const f32x4*)(pBg + k1 + 32772);
    }
    short8 afr[4], bfr[4];
#pragma unroll
    for (int i = 0; i < 4; ++i) {
      afr[i] = *(const short8*)&Ab[cur][(wm + i * 16 + fr) * 40 + fg * 8];
      bfr[i] = *(const short8*)&Bb[cur][(wn + i * 16 + fr) * 40 + fg * 8];
    }
#pragma unroll
    for (int i = 0; i < 4; ++i)
#pragma unroll
      for (int j = 0; j < 4; ++j)
        acc[i][j] = __builtin_amdgcn_mfma_f32_16x16x32_bf16(afr[i], bfr[j], acc[i][j], 0, 0, 0);
    if (step < 15) {
      const int nxt = cur ^ 1;
      *(short8*)&Ab[nxt][sr * 40 + sk] = pack8(a0, a1);
      *(short8*)&Ab[nxt][(sr + 64) * 40 + sk] = pack8(a2, a3);
      *(short8*)&Bb[nxt][sr * 40 + sk] = pack8(b0, b1);
      *(short8*)&Bb[nxt][(sr + 64) * 40 + sk] = pack8(b2, b3);
    }
    __syncthreads();
  }
#pragma unroll
  for (int i = 0; i < 4; ++i)
#pragma unroll
    for (int j = 0; j < 4; ++j)
#pragma unroll
      for (int r = 0; r < 4; ++r) {
        const int row = m0 + wm + i * 16 + fg * 4 + r;   // C/D: row=(lane>>4)*4+reg
        const int col = n0 + wn + j * 16 + fr;           //      col=lane&15
        outp[(size_t)row * 512 + col] = f2bf(acc[i][j][r]);
      }
}

// ---------------- K2: G partials = sum_s K'[s,hd]*V'[s,he] over s-chunks ----------------
__global__ __launch_bounds__(256) void gpart_kernel(const unsigned short* __restrict__ Kp,
                                                    const unsigned short* __restrict__ Vp,
                                                    float* __restrict__ Gpart) {
  __shared__ float Kl[16][64];
  __shared__ float Vl[16][64];
  const int t = threadIdx.x;
  const int chunk = blockIdx.x;   // 16
  const int bh = blockIdx.y;      // 32
  const int b = bh >> 3, h = bh & 7;
  const int s0 = chunk * 512;
  const int d0 = (t >> 4) * 4;
  const int e0 = (t & 15) * 4;
  const int isV = t >> 7;
  const int rr = (t & 127) >> 3;
  const int cc = (t & 7) * 8;
  const unsigned short* src = (isV ? Vp : Kp) + (size_t)(b * 8192 + s0) * 512 + h * 64 + cc;
  float* dl = (isV ? &Vl[0][0] : &Kl[0][0]) + rr * 64 + cc;
  float acc[4][4] = {};
  for (int ss = 0; ss < 512; ss += 16) {
    short8 u = *(const short8*)(src + (size_t)(ss + rr) * 512);
#pragma unroll
    for (int i = 0; i < 8; ++i) dl[i] = bf2f((unsigned short)u[i]);
    __syncthreads();
#pragma unroll
    for (int qq = 0; qq < 16; ++qq) {
      f32x4 kv = *(const f32x4*)&Kl[qq][d0];
      f32x4 vv = *(const f32x4*)&Vl[qq][e0];
#pragma unroll
      for (int i = 0; i < 4; ++i)
#pragma unroll
        for (int j = 0; j < 4; ++j)
          acc[i][j] += kv[i] * vv[j];
    }
    __syncthreads();
  }
  float* gp = Gpart + ((size_t)chunk * 32 + bh) * 4096;
#pragma unroll
  for (int i = 0; i < 4; ++i)
#pragma unroll
    for (int j = 0; j < 4; ++j)
      gp[(d0 + i) * 64 + (e0 + j)] = acc[i][j];
}

// ---------------- K2b: Gsum = SCALE^2 * sum_chunks Gpart ----------------
__global__ __launch_bounds__(256) void gsum_kernel(const float* __restrict__ Gpart,
                                                   float* __restrict__ Gsum) {
  const int idx = blockIdx.x * 256 + threadIdx.x;  // 131072 total
  float s = 0.f;
#pragma unroll
  for (int c = 0; c < 16; ++c) s += Gpart[(size_t)c * 131072 + idx];
  Gsum[idx] = s * (1.0f / 64.0f);  // SCALE^2 = 1/dk
}

// ---------------- K3a: T3[b][c][h*64+e] = sum_d Wq[h*64+d][c] * G[b,h,d,e] -> bf16 ----------------
__global__ __launch_bounds__(256) void t3_kernel(const float* __restrict__ Wq,
                                                 const float* __restrict__ Gsum,
                                                 unsigned short* __restrict__ T3) {
  __shared__ float Wl[64][64];
  __shared__ float Gl[64][64];
  const int t = threadIdx.x;
  const int c0 = blockIdx.x * 64;
  const int h = blockIdx.y;
  const int b = blockIdx.z;
  const int dd = t >> 2;
  const int c4 = (t & 3) * 16;
  const float* wp = Wq + (size_t)(h * 64 + dd) * 512 + c0 + c4;
  const float* gp = Gsum + (size_t)(b * 8 + h) * 4096 + dd * 64 + c4;
#pragma unroll
  for (int i = 0; i < 4; ++i) {
    *(f32x4*)&Wl[dd][c4 + i * 4] = *(const f32x4*)(wp + i * 4);
    *(f32x4*)&Gl[dd][c4 + i * 4] = *(const f32x4*)(gp + i * 4);
  }
  __syncthreads();
  const int cl0 = (t >> 4) * 4;
  const int e0 = (t & 15) * 4;
  float acc[4][4] = {};
  for (int d = 0; d < 64; ++d) {
    f32x4 wv = *(const f32x4*)&Wl[d][cl0];
    f32x4 gv = *(const f32x4*)&Gl[d][e0];
#pragma unroll
    for (int i = 0; i < 4; ++i)
#pragma unroll
      for (int j = 0; j < 4; ++j)
        acc[i][j] += wv[i] * gv[j];
  }
#pragma unroll
  for (int i = 0; i < 4; ++i)
#pragma unroll
    for (int j = 0; j < 4; ++j)
      T3[((size_t)b * 512 + c0 + cl0 + i) * 512 + h * 64 + e0 + j] = f2bf(acc[i][j]);
}

// ---------------- K3b: WcT[b][n][c] = sum_j Wo[n][j] * T3[b][c][j] -> bf16 ----------------
__global__ __launch_bounds__(64) void wc_kernel(const float* __restrict__ Wo,
                                                const unsigned short* __restrict__ T3,
                                                unsigned short* __restrict__ WcT) {
  __shared__ __align__(16) unsigned short Ao[64 * 48];
  __shared__ __align__(16) unsigned short Bo[64 * 48];
  const int t = threadIdx.x;  // 0..63
  const int n0 = blockIdx.x * 64;
  const int c0 = blockIdx.y * 64;
  const int b = blockIdx.z;
  const int fr = t & 15, fg = t >> 4;
  f32x4 acc[4][4] = {};
  for (int step = 0; step < 16; ++step) {
    const int k0 = step * 32;
    const float* pa = Wo + (size_t)(n0 + t) * 512 + k0;
    unsigned short tmp[32];
#pragma unroll
    for (int i = 0; i < 8; ++i) {
      f32x4 vv = *(const f32x4*)(pa + i * 4);
#pragma unroll
      for (int j = 0; j < 4; ++j) tmp[i * 4 + j] = f2bf(vv[j]);
    }
#pragma unroll
    for (int i = 0; i < 4; ++i) *(short8*)&Ao[t * 48 + i * 8] = *(const short8*)&tmp[i * 8];
    const unsigned short* pb = T3 + ((size_t)b * 512 + c0 + t) * 512 + k0;
#pragma unroll
    for (int i = 0; i < 4; ++i) *(short8*)&Bo[t * 48 + i * 8] = *(const short8*)(pb + i * 8);
    __syncthreads();
    short8 afr[4], bfr[4];
#pragma unroll
    for (int i = 0; i < 4; ++i) {
      afr[i] = *(const short8*)&Ao[(i * 16 + fr) * 48 + fg * 8];
      bfr[i] = *(const short8*)&Bo[(i * 16 + fr) * 48 + fg * 8];
    }
#pragma unroll
    for (int i = 0; i < 4; ++i)
#pragma unroll
      for (int j = 0; j < 4; ++j)
        acc[i][j] = __builtin_amdgcn_mfma_f32_16x16x32_bf16(afr[i], bfr[j], acc[i][j], 0, 0, 0);
    __syncthreads();
  }
#pragma unroll
  for (int i = 0; i < 4; ++i)
#pragma unroll
    for (int j = 0; j < 4; ++j)
#pragma unroll
      for (int r = 0; r < 4; ++r)
        WcT[((size_t)b * 512 + n0 + i * 16 + fg * 4 + r) * 512 + c0 + j * 16 + fr] =
            f2bf(acc[i][j][r]);
}

// ---------------- K4: Out = q @ Wc[b] + b_o -> f32 (2-phase pipeline) ----------------
__global__ __launch_bounds__(256, 3) void out_kernel(const float* __restrict__ q,
                                                     const unsigned short* __restrict__ WcT,
                                                     const float* __restrict__ bo,
                                                     float* __restrict__ Out) {
  __shared__ __align__(16) unsigned short Ab[2][128 * 40];
  __shared__ __align__(16) unsigned short Bb[2][128 * 40];
  const int t = threadIdx.x;
  const int n0 = blockIdx.x * 128;
  const int m0 = blockIdx.y * 128;
  const unsigned short* Wc = WcT + ((size_t)(m0 >> 13)) * 512 * 512;  // batch = m0/8192
  const int lane = t & 63, w = t >> 6;
  const int wm = (w >> 1) * 64, wn = (w & 1) * 64;
  const int fr = lane & 15, fg = lane >> 4;
  const int sr = t >> 2;
  const int sk = (t & 3) * 8;

  const float* pAg = q + (size_t)(m0 + sr) * 512 + sk;
  const unsigned short* pBg = Wc + (size_t)(n0 + sr) * 512 + sk;

  f32x4 acc[4][4] = {};
  f32x4 a0, a1, a2, a3;
  short8 sb0, sb1;

  a0 = *(const f32x4*)(pAg);         a1 = *(const f32x4*)(pAg + 4);
  a2 = *(const f32x4*)(pAg + 32768); a3 = *(const f32x4*)(pAg + 32772);
  sb0 = *(const short8*)(pBg);
  sb1 = *(const short8*)(pBg + 32768);
  *(short8*)&Ab[0][sr * 40 + sk] = pack8(a0, a1);
  *(short8*)&Ab[0][(sr + 64) * 40 + sk] = pack8(a2, a3);
  *(short8*)&Bb[0][sr * 40 + sk] = sb0;
  *(short8*)&Bb[0][(sr + 64) * 40 + sk] = sb1;
  __syncthreads();

  for (int step = 0; step < 16; ++step) {
    const int cur = step & 1;
    if (step < 15) {
      const int k1 = (step + 1) * 32;
      a0 = *(const f32x4*)(pAg + k1);         a1 = *(const f32x4*)(pAg + k1 + 4);
      a2 = *(const f32x4*)(pAg + k1 + 32768); a3 = *(const f32x4*)(pAg + k1 + 32772);
      sb0 = *(const short8*)(pBg + k1);
      sb1 = *(const short8*)(pBg + k1 + 32768);
    }
    short8 afr[4], bfr[4];
#pragma unroll
    for (int i = 0; i < 4; ++i) {
      afr[i] = *(const short8*)&Ab[cur][(wm + i * 16 + fr) * 40 + fg * 8];
      bfr[i] = *(const short8*)&Bb[cur][(wn + i * 16 + fr) * 40 + fg * 8];
    }
#pragma unroll
    for (int i = 0; i < 4; ++i)
#pragma unroll
      for (int j = 0; j < 4; ++j)
        acc[i][j] = __builtin_amdgcn_mfma_f32_16x16x32_bf16(afr[i], bfr[j], acc[i][j], 0, 0, 0);
    if (step < 15) {
      const int nxt = cur ^ 1;
      *(short8*)&Ab[nxt][sr * 40 + sk] = pack8(a0, a1);
      *(short8*)&Ab[nxt][(sr + 64) * 40 + sk] = pack8(a2, a3);
      *(short8*)&Bb[nxt][sr * 40 + sk] = sb0;
      *(short8*)&Bb[nxt][(sr + 64) * 40 + sk] = sb1;
    }
    __syncthreads();
  }
  float bias[4];
#pragma unroll
  for (int j = 0; j < 4; ++j) bias[j] = bo[n0 + wn + j * 16 + fr];
#pragma unroll
  for (int i = 0; i < 4; ++i)
#pragma unroll
    for (int j = 0; j < 4; ++j)
#pragma unroll
      for (int r = 0; r < 4; ++r) {
        const int row = m0 + wm + i * 16 + fg * 4 + r;
        const int col = n0 + wn + j * 16 + fr;
        Out[(size_t)row * 512 + col] = acc[i][j][r] + bias[j];
      }
}

extern "C" void kernel_launch(void* const* d_in, const int* in_sizes, int n_in,
                              void* d_out, int out_size, void* d_ws, size_t ws_size,
                              hipStream_t stream) {
  const float* q  = (const float*)d_in[0];
  const float* k  = (const float*)d_in[1];
  const float* v  = (const float*)d_in[2];
  const float* Wq = (const float*)d_in[3];
  const float* Wk = (const float*)d_in[4];
  const float* Wv = (const float*)d_in[5];
  const float* Wo = (const float*)d_in[6];
  const float* bo = (const float*)d_in[7];
  float* Out = (float*)d_out;

  // K'/V' (bf16, 32MB each) live inside d_out (64MB) until out_kernel overwrites it.
  unsigned short* Kp = (unsigned short*)d_out;
  unsigned short* Vp = Kp + (size_t)16777216;
  char* ws = (char*)d_ws;
  float* Gpart        = (float*)ws;                                   // 8 MB
  float* Gsum         = (float*)(ws + (size_t)8  * 1048576);          // 0.5 MB
  unsigned short* T3  = (unsigned short*)(ws + (size_t)9  * 1048576); // 2 MB
  unsigned short* WcT = (unsigned short*)(ws + (size_t)11 * 1048576); // 2 MB

  proj2_kernel<<<dim3(4, 256, 2), dim3(256), 0, stream>>>(k, v, Wk, Wv, Kp);
  gpart_kernel<<<dim3(16, 32), dim3(256), 0, stream>>>(Kp, Vp, Gpart);
  gsum_kernel<<<dim3(512), dim3(256), 0, stream>>>(Gpart, Gsum);
  t3_kernel<<<dim3(8, 8, 4), dim3(256), 0, stream>>>(Wq, Gsum, T3);
  wc_kernel<<<dim3(8, 8, 4), dim3(64), 0, stream>>>(Wo, T3, WcT);
  out_kernel<<<dim3(4, 256), dim3(256), 0, stream>>>(q, WcT, bo, Out);
}

// Round 4
// 210.441 us; speedup vs baseline: 1.0608x; 1.0352x over previous
//
#include <hip/hip_runtime.h>
#include <hip/hip_bf16.h>

// LinMHA via full algebraic collapse:
//   M~_b = v_b^T k_b                  (512x512 per batch, bf16 MFMA, split-K=8)
//   P_b  = Wk @ M~_b^T                (P[hd][c'] = sum_c Wk[hd][c] M~[c'][c])
//   G_bh = SCALE^2 * P_bh @ Wv_h^T    (64x64 head blocks)
//   Wc_b = Wq^T blockdiag(G_b) Wo^T   (t3 + wc)
//   Out  = q @ Wc_b + b_o
// B=4, S=8192, C=512, H=8, DK=64.

typedef __attribute__((ext_vector_type(4))) float f32x4;
typedef __attribute__((ext_vector_type(8))) short short8;
typedef __attribute__((ext_vector_type(4))) unsigned short ushort4_t;

#define DEVI __device__ __forceinline__

DEVI unsigned short f2bf(float f) {
  unsigned int u = __builtin_bit_cast(unsigned int, f);
  u += 0x7fffu + ((u >> 16) & 1u);   // RNE
  return (unsigned short)(u >> 16);
}
DEVI float bf2f(unsigned short s) {
  unsigned int u = ((unsigned int)s) << 16;
  return __builtin_bit_cast(float, u);
}
DEVI short8 pack8(f32x4 a, f32x4 b) {
  short8 r;
#pragma unroll
  for (int i = 0; i < 4; ++i) { r[i] = (short)f2bf(a[i]); r[i + 4] = (short)f2bf(b[i]); }
  return r;
}

// ---------------- K1: M~ partials = v^T k over s-chunks (bf16 MFMA) ----------------
// grid 512: (b,split) pair pinned to one XCD (16 tiles of 128x128 each).
// LDS tiles stored TRANSPOSED [c][s] (pitch 40 shorts): staging threads load 4 s-rows x 8 c
// from global, pack per-column ushort4 (4 s) and do plain b64 LDS stores. Fragment reads are
// contiguous short8 (ds_read_b128) like the validated TN-GEMM skeleton. No inline asm.
__global__ __launch_bounds__(256, 2) void bigm_kernel(const float* __restrict__ kmat,
                                                      const float* __restrict__ vmat,
                                                      float* __restrict__ Mpart) {
  __shared__ __align__(16) unsigned short Vt[2][128 * 40];
  __shared__ __align__(16) unsigned short Kt[2][128 * 40];
  const int t = threadIdx.x;
  const int bid = blockIdx.x;
  const int xcd = bid & 7, jj = bid >> 3;
  const int p = ((jj >> 4) << 3) | xcd;        // 0..31 = b*8+split
  const int tile = jj & 15;
  const int b = p >> 3, split = p & 7;
  const int ti = tile >> 2, tj = tile & 3;
  const int cp0 = ti * 128, ck0 = tj * 128;    // c' tile (v-cols), c tile (k-cols)

  const int lane = t & 63, w = t >> 6;
  const int fr = lane & 15, fg = lane >> 4;
  const int wm = (w >> 1) * 64, wn = (w & 1) * 64;

  // staging decomposition: half = t>>7 (0:V, 1:K); u = t&127: co = c-oct, sq = s-quad
  const int half = t >> 7;
  const int u = t & 127;
  const int co = u & 15, sq = u >> 4;
  const float* srcg = (half ? kmat : vmat)
                    + ((size_t)b * 8192 + (size_t)split * 1024) * 512
                    + (half ? ck0 : cp0) + co * 8;
  unsigned short* dstl = (half ? &Kt[0][0] : &Vt[0][0]) + (co * 8) * 40 + sq * 4;

  f32x4 r0a, r0b, r1a, r1b, r2a, r2b, r3a, r3b;

  // load 4 consecutive s-rows (s = sbase + sq*4 + 0..3), 8 c each
  auto gload = [&](int sbase) {
    const float* pp = srcg + (size_t)(sbase + sq * 4) * 512;
    r0a = *(const f32x4*)(pp);          r0b = *(const f32x4*)(pp + 4);
    r1a = *(const f32x4*)(pp + 512);    r1b = *(const f32x4*)(pp + 516);
    r2a = *(const f32x4*)(pp + 1024);   r2b = *(const f32x4*)(pp + 1028);
    r3a = *(const f32x4*)(pp + 1536);   r3b = *(const f32x4*)(pp + 1540);
  };
  // transposed LDS store: per column c, pack 4 s-values -> one b64 store
  auto lwrite = [&](int buf) {
    unsigned short* d = dstl + buf * (128 * 40);
#pragma unroll
    for (int ci = 0; ci < 4; ++ci) {
      ushort4_t wlo;
      wlo[0] = f2bf(r0a[ci]); wlo[1] = f2bf(r1a[ci]);
      wlo[2] = f2bf(r2a[ci]); wlo[3] = f2bf(r3a[ci]);
      *(ushort4_t*)(d + ci * 40) = wlo;
      ushort4_t whi;
      whi[0] = f2bf(r0b[ci]); whi[1] = f2bf(r1b[ci]);
      whi[2] = f2bf(r2b[ci]); whi[3] = f2bf(r3b[ci]);
      *(ushort4_t*)(d + (ci + 4) * 40) = whi;
    }
  };

  f32x4 acc[4][4] = {};

  gload(0);
  lwrite(0);
  __syncthreads();

  for (int step = 0; step < 32; ++step) {
    const int cur = step & 1;
    if (step < 31) gload((step + 1) * 32);
    short8 fa[4], fb[4];
#pragma unroll
    for (int i = 0; i < 4; ++i) {
      fa[i] = *(const short8*)&Vt[cur][(wm + i * 16 + fr) * 40 + fg * 8];
      fb[i] = *(const short8*)&Kt[cur][(wn + i * 16 + fr) * 40 + fg * 8];
    }
#pragma unroll
    for (int i = 0; i < 4; ++i)
#pragma unroll
      for (int j = 0; j < 4; ++j)
        acc[i][j] = __builtin_amdgcn_mfma_f32_16x16x32_bf16(fa[i], fb[j], acc[i][j], 0, 0, 0);
    if (step < 31) lwrite(cur ^ 1);
    __syncthreads();
  }
  // acc[i][j]: row = c' (A=Vt row), col = c (B=Kt row)
  float* gp = Mpart + (size_t)p * 262144;
#pragma unroll
  for (int i = 0; i < 4; ++i)
#pragma unroll
    for (int j = 0; j < 4; ++j)
#pragma unroll
      for (int r = 0; r < 4; ++r)
        gp[(size_t)(cp0 + wm + i * 16 + fg * 4 + r) * 512 + ck0 + wn + j * 16 + fr] = acc[i][j][r];
}

// ---------------- K2: Msum = sum_splits Mpart -> bf16 [b][c'][c] ----------------
__global__ __launch_bounds__(256) void mred_kernel(const float* __restrict__ Mpart,
                                                   unsigned short* __restrict__ Msum) {
  const int idx = blockIdx.x * 256 + threadIdx.x;  // 1048576 total
  const int b = idx >> 18;
  const int r = idx & 262143;
  const float* src = Mpart + (size_t)(b * 8) * 262144 + r;
  float s = 0.f;
#pragma unroll
  for (int c = 0; c < 8; ++c) s += src[(size_t)c * 262144];
  Msum[idx] = f2bf(s);
}

// ---------------- K3: P_b[hd][c'] = sum_c Wk[hd][c] * Msum_b[c'][c] -> bf16 ----------------
__global__ __launch_bounds__(256, 3) void stepa_kernel(const float* __restrict__ Wk,
                                                       const unsigned short* __restrict__ Msum,
                                                       unsigned short* __restrict__ P) {
  __shared__ __align__(16) unsigned short Ab[2][128 * 40];
  __shared__ __align__(16) unsigned short Bb[2][128 * 40];
  const int t = threadIdx.x;
  const int n0 = blockIdx.x * 128;   // c'
  const int m0 = blockIdx.y * 128;   // hd
  const int b = blockIdx.z;
  const int lane = t & 63, w = t >> 6;
  const int wm = (w >> 1) * 64, wn = (w & 1) * 64;
  const int fr = lane & 15, fg = lane >> 4;
  const int sr = t >> 2;
  const int sk = (t & 3) * 8;

  const float* pAg = Wk + (size_t)(m0 + sr) * 512 + sk;
  const unsigned short* pBg = Msum + (size_t)b * 262144 + (size_t)(n0 + sr) * 512 + sk;

  f32x4 acc[4][4] = {};
  f32x4 a0, a1, a2, a3;
  short8 sb0, sb1;

  a0 = *(const f32x4*)(pAg);         a1 = *(const f32x4*)(pAg + 4);
  a2 = *(const f32x4*)(pAg + 32768); a3 = *(const f32x4*)(pAg + 32772);
  sb0 = *(const short8*)(pBg);
  sb1 = *(const short8*)(pBg + 32768);
  *(short8*)&Ab[0][sr * 40 + sk] = pack8(a0, a1);
  *(short8*)&Ab[0][(sr + 64) * 40 + sk] = pack8(a2, a3);
  *(short8*)&Bb[0][sr * 40 + sk] = sb0;
  *(short8*)&Bb[0][(sr + 64) * 40 + sk] = sb1;
  __syncthreads();

  for (int step = 0; step < 16; ++step) {
    const int cur = step & 1;
    if (step < 15) {
      const int k1 = (step + 1) * 32;
      a0 = *(const f32x4*)(pAg + k1);         a1 = *(const f32x4*)(pAg + k1 + 4);
      a2 = *(const f32x4*)(pAg + k1 + 32768); a3 = *(const f32x4*)(pAg + k1 + 32772);
      sb0 = *(const short8*)(pBg + k1);
      sb1 = *(const short8*)(pBg + k1 + 32768);
    }
    short8 afr[4], bfr[4];
#pragma unroll
    for (int i = 0; i < 4; ++i) {
      afr[i] = *(const short8*)&Ab[cur][(wm + i * 16 + fr) * 40 + fg * 8];
      bfr[i] = *(const short8*)&Bb[cur][(wn + i * 16 + fr) * 40 + fg * 8];
    }
#pragma unroll
    for (int i = 0; i < 4; ++i)
#pragma unroll
      for (int j = 0; j < 4; ++j)
        acc[i][j] = __builtin_amdgcn_mfma_f32_16x16x32_bf16(afr[i], bfr[j], acc[i][j], 0, 0, 0);
    if (step < 15) {
      const int nxt = cur ^ 1;
      *(short8*)&Ab[nxt][sr * 40 + sk] = pack8(a0, a1);
      *(short8*)&Ab[nxt][(sr + 64) * 40 + sk] = pack8(a2, a3);
      *(short8*)&Bb[nxt][sr * 40 + sk] = sb0;
      *(short8*)&Bb[nxt][(sr + 64) * 40 + sk] = sb1;
    }
    __syncthreads();
  }
#pragma unroll
  for (int i = 0; i < 4; ++i)
#pragma unroll
    for (int j = 0; j < 4; ++j)
#pragma unroll
      for (int r = 0; r < 4; ++r) {
        const int row = m0 + wm + i * 16 + fg * 4 + r;   // hd
        const int col = n0 + wn + j * 16 + fr;           // c'
        P[((size_t)b * 512 + row) * 512 + col] = f2bf(acc[i][j][r]);
      }
}

// ---------------- K4: G[b,h][d][e] = SCALE^2 * sum_c' P[hd][c'] Wv[he][c'] -> f32 ----------------
__global__ __launch_bounds__(64) void stepb_kernel(const unsigned short* __restrict__ P,
                                                   const float* __restrict__ Wv,
                                                   float* __restrict__ Gsum) {
  __shared__ __align__(16) unsigned short Ao[64 * 40];
  __shared__ __align__(16) unsigned short Bo[64 * 40];
  const int t = threadIdx.x;  // 0..63
  const int h = blockIdx.x;
  const int b = blockIdx.y;
  const int fr = t & 15, fg = t >> 4;
  f32x4 acc[4][4] = {};
  for (int step = 0; step < 16; ++step) {
    const int k0 = step * 32;
    const unsigned short* pa = P + ((size_t)b * 512 + h * 64 + t) * 512 + k0;
#pragma unroll
    for (int i = 0; i < 4; ++i) *(short8*)&Ao[t * 40 + i * 8] = *(const short8*)(pa + i * 8);
    const float* pb = Wv + (size_t)(h * 64 + t) * 512 + k0;
#pragma unroll
    for (int i = 0; i < 4; ++i) {
      f32x4 x0 = *(const f32x4*)(pb + i * 8);
      f32x4 x1 = *(const f32x4*)(pb + i * 8 + 4);
      *(short8*)&Bo[t * 40 + i * 8] = pack8(x0, x1);
    }
    __syncthreads();
    short8 afr[4], bfr[4];
#pragma unroll
    for (int i = 0; i < 4; ++i) {
      afr[i] = *(const short8*)&Ao[(i * 16 + fr) * 40 + fg * 8];
      bfr[i] = *(const short8*)&Bo[(i * 16 + fr) * 40 + fg * 8];
    }
#pragma unroll
    for (int i = 0; i < 4; ++i)
#pragma unroll
      for (int j = 0; j < 4; ++j)
        acc[i][j] = __builtin_amdgcn_mfma_f32_16x16x32_bf16(afr[i], bfr[j], acc[i][j], 0, 0, 0);
    __syncthreads();
  }
  float* gout = Gsum + (size_t)(b * 8 + h) * 4096;
#pragma unroll
  for (int i = 0; i < 4; ++i)
#pragma unroll
    for (int j = 0; j < 4; ++j)
#pragma unroll
      for (int r = 0; r < 4; ++r)
        gout[(i * 16 + fg * 4 + r) * 64 + (j * 16 + fr)] = acc[i][j][r] * 0.015625f;  // SCALE^2
}

// ---------------- K5: T3[b][c][h*64+e] = sum_d Wq[h*64+d][c] * G[b,h,d,e] -> bf16 ----------------
__global__ __launch_bounds__(256) void t3_kernel(const float* __restrict__ Wq,
                                                 const float* __restrict__ Gsum,
                                                 unsigned short* __restrict__ T3) {
  __shared__ float Wl[64][64];
  __shared__ float Gl[64][64];
  const int t = threadIdx.x;
  const int c0 = blockIdx.x * 64;
  const int h = blockIdx.y;
  const int b = blockIdx.z;
  const int dd = t >> 2;
  const int c4 = (t & 3) * 16;
  const float* wp = Wq + (size_t)(h * 64 + dd) * 512 + c0 + c4;
  const float* gp = Gsum + (size_t)(b * 8 + h) * 4096 + dd * 64 + c4;
#pragma unroll
  for (int i = 0; i < 4; ++i) {
    *(f32x4*)&Wl[dd][c4 + i * 4] = *(const f32x4*)(wp + i * 4);
    *(f32x4*)&Gl[dd][c4 + i * 4] = *(const f32x4*)(gp + i * 4);
  }
  __syncthreads();
  const int cl0 = (t >> 4) * 4;
  const int e0 = (t & 15) * 4;
  float acc[4][4] = {};
  for (int d = 0; d < 64; ++d) {
    f32x4 wv = *(const f32x4*)&Wl[d][cl0];
    f32x4 gv = *(const f32x4*)&Gl[d][e0];
#pragma unroll
    for (int i = 0; i < 4; ++i)
#pragma unroll
      for (int j = 0; j < 4; ++j)
        acc[i][j] += wv[i] * gv[j];
  }
#pragma unroll
  for (int i = 0; i < 4; ++i)
#pragma unroll
    for (int j = 0; j < 4; ++j)
      T3[((size_t)b * 512 + c0 + cl0 + i) * 512 + h * 64 + e0 + j] = f2bf(acc[i][j]);
}

// ---------------- K6: WcT[b][n][c] = sum_j Wo[n][j] * T3[b][c][j] -> bf16 ----------------
__global__ __launch_bounds__(64) void wc_kernel(const float* __restrict__ Wo,
                                                const unsigned short* __restrict__ T3,
                                                unsigned short* __restrict__ WcT) {
  __shared__ __align__(16) unsigned short Ao[64 * 48];
  __shared__ __align__(16) unsigned short Bo[64 * 48];
  const int t = threadIdx.x;  // 0..63
  const int n0 = blockIdx.x * 64;
  const int c0 = blockIdx.y * 64;
  const int b = blockIdx.z;
  const int fr = t & 15, fg = t >> 4;
  f32x4 acc[4][4] = {};
  for (int step = 0; step < 16; ++step) {
    const int k0 = step * 32;
    const float* pa = Wo + (size_t)(n0 + t) * 512 + k0;
    unsigned short tmp[32];
#pragma unroll
    for (int i = 0; i < 8; ++i) {
      f32x4 vv = *(const f32x4*)(pa + i * 4);
#pragma unroll
      for (int j = 0; j < 4; ++j) tmp[i * 4 + j] = f2bf(vv[j]);
    }
#pragma unroll
    for (int i = 0; i < 4; ++i) *(short8*)&Ao[t * 48 + i * 8] = *(const short8*)&tmp[i * 8];
    const unsigned short* pb = T3 + ((size_t)b * 512 + c0 + t) * 512 + k0;
#pragma unroll
    for (int i = 0; i < 4; ++i) *(short8*)&Bo[t * 48 + i * 8] = *(const short8*)(pb + i * 8);
    __syncthreads();
    short8 afr[4], bfr[4];
#pragma unroll
    for (int i = 0; i < 4; ++i) {
      afr[i] = *(const short8*)&Ao[(i * 16 + fr) * 48 + fg * 8];
      bfr[i] = *(const short8*)&Bo[(i * 16 + fr) * 48 + fg * 8];
    }
#pragma unroll
    for (int i = 0; i < 4; ++i)
#pragma unroll
      for (int j = 0; j < 4; ++j)
        acc[i][j] = __builtin_amdgcn_mfma_f32_16x16x32_bf16(afr[i], bfr[j], acc[i][j], 0, 0, 0);
    __syncthreads();
  }
#pragma unroll
  for (int i = 0; i < 4; ++i)
#pragma unroll
    for (int j = 0; j < 4; ++j)
#pragma unroll
      for (int r = 0; r < 4; ++r)
        WcT[((size_t)b * 512 + n0 + i * 16 + fg * 4 + r) * 512 + c0 + j * 16 + fr] =
            f2bf(acc[i][j][r]);
}

// ---------------- K7: Out = q @ Wc[b] + b_o -> f32 (2-phase, XCD-grouped) ----------------
__global__ __launch_bounds__(256, 3) void out_kernel(const float* __restrict__ q,
                                                     const unsigned short* __restrict__ WcT,
                                                     const float* __restrict__ bo,
                                                     float* __restrict__ Out) {
  __shared__ __align__(16) unsigned short Ab[2][128 * 40];
  __shared__ __align__(16) unsigned short Bb[2][128 * 40];
  const int t = threadIdx.x;
  const int bid = blockIdx.x;
  const int xcd = bid & 7, idx = bid >> 3;
  const int mt = xcd * 32 + (idx >> 2);
  const int nt = idx & 3;
  const int m0 = mt * 128, n0 = nt * 128;
  const unsigned short* Wc = WcT + ((size_t)(m0 >> 13)) * 512 * 512;  // batch = m0/8192
  const int lane = t & 63, w = t >> 6;
  const int wm = (w >> 1) * 64, wn = (w & 1) * 64;
  const int fr = lane & 15, fg = lane >> 4;
  const int sr = t >> 2;
  const int sk = (t & 3) * 8;

  const float* pAg = q + (size_t)(m0 + sr) * 512 + sk;
  const unsigned short* pBg = Wc + (size_t)(n0 + sr) * 512 + sk;

  f32x4 acc[4][4] = {};
  f32x4 a0, a1, a2, a3;
  short8 sb0, sb1;

  a0 = *(const f32x4*)(pAg);         a1 = *(const f32x4*)(pAg + 4);
  a2 = *(const f32x4*)(pAg + 32768); a3 = *(const f32x4*)(pAg + 32772);
  sb0 = *(const short8*)(pBg);
  sb1 = *(const short8*)(pBg + 32768);
  *(short8*)&Ab[0][sr * 40 + sk] = pack8(a0, a1);
  *(short8*)&Ab[0][(sr + 64) * 40 + sk] = pack8(a2, a3);
  *(short8*)&Bb[0][sr * 40 + sk] = sb0;
  *(short8*)&Bb[0][(sr + 64) * 40 + sk] = sb1;
  __syncthreads();

  for (int step = 0; step < 16; ++step) {
    const int cur = step & 1;
    if (step < 15) {
      const int k1 = (step + 1) * 32;
      a0 = *(const f32x4*)(pAg + k1);         a1 = *(const f32x4*)(pAg + k1 + 4);
      a2 = *(const f32x4*)(pAg + k1 + 32768); a3 = *(const f32x4*)(pAg + k1 + 32772);
      sb0 = *(const short8*)(pBg + k1);
      sb1 = *(const short8*)(pBg + k1 + 32768);
    }
    short8 afr[4], bfr[4];
#pragma unroll
    for (int i = 0; i < 4; ++i) {
      afr[i] = *(const short8*)&Ab[cur][(wm + i * 16 + fr) * 40 + fg * 8];
      bfr[i] = *(const short8*)&Bb[cur][(wn + i * 16 + fr) * 40 + fg * 8];
    }
#pragma unroll
    for (int i = 0; i < 4; ++i)
#pragma unroll
      for (int j = 0; j < 4; ++j)
        acc[i][j] = __builtin_amdgcn_mfma_f32_16x16x32_bf16(afr[i], bfr[j], acc[i][j], 0, 0, 0);
    if (step < 15) {
      const int nxt = cur ^ 1;
      *(short8*)&Ab[nxt][sr * 40 + sk] = pack8(a0, a1);
      *(short8*)&Ab[nxt][(sr + 64) * 40 + sk] = pack8(a2, a3);
      *(short8*)&Bb[nxt][sr * 40 + sk] = sb0;
      *(short8*)&Bb[nxt][(sr + 64) * 40 + sk] = sb1;
    }
    __syncthreads();
  }
  float bias[4];
#pragma unroll
  for (int j = 0; j < 4; ++j) bias[j] = bo[n0 + wn + j * 16 + fr];
#pragma unroll
  for (int i = 0; i < 4; ++i)
#pragma unroll
    for (int j = 0; j < 4; ++j)
#pragma unroll
      for (int r = 0; r < 4; ++r) {
        const int row = m0 + wm + i * 16 + fg * 4 + r;
        const int col = n0 + wn + j * 16 + fr;
        Out[(size_t)row * 512 + col] = acc[i][j][r] + bias[j];
      }
}

extern "C" void kernel_launch(void* const* d_in, const int* in_sizes, int n_in,
                              void* d_out, int out_size, void* d_ws, size_t ws_size,
                              hipStream_t stream) {
  const float* q  = (const float*)d_in[0];
  const float* k  = (const float*)d_in[1];
  const float* v  = (const float*)d_in[2];
  const float* Wq = (const float*)d_in[3];
  const float* Wk = (const float*)d_in[4];
  const float* Wv = (const float*)d_in[5];
  const float* Wo = (const float*)d_in[6];
  const float* bo = (const float*)d_in[7];
  float* Out = (float*)d_out;

  // Mpart (32 MB f32) lives inside d_out (64 MB) until out_kernel overwrites it.
  float* Mpart = (float*)d_out;
  char* ws = (char*)d_ws;
  unsigned short* Msum = (unsigned short*)ws;                          // 2 MB
  unsigned short* P    = (unsigned short*)(ws + (size_t)2 * 1048576);  // 2 MB
  float* Gsum          = (float*)(ws + (size_t)4 * 1048576);           // 0.5 MB
  unsigned short* T3   = (unsigned short*)(ws + (size_t)5 * 1048576);  // 2 MB
  unsigned short* WcT  = (unsigned short*)(ws + (size_t)7 * 1048576);  // 2 MB

  bigm_kernel<<<512, 256, 0, stream>>>(k, v, Mpart);
  mred_kernel<<<4096, 256, 0, stream>>>(Mpart, Msum);
  stepa_kernel<<<dim3(4, 4, 4), 256, 0, stream>>>(Wk, Msum, P);
  stepb_kernel<<<dim3(8, 4), 64, 0, stream>>>(P, Wv, Gsum);
  t3_kernel<<<dim3(8, 8, 4), 256, 0, stream>>>(Wq, Gsum, T3);
  wc_kernel<<<dim3(8, 8, 4), 64, 0, stream>>>(Wo, T3, WcT);
  out_kernel<<<1024, 256, 0, stream>>>(q, WcT, bo, Out);
}

// Round 5
// 172.668 us; speedup vs baseline: 1.2929x; 1.2188x over previous
//
#include <hip/hip_runtime.h>
#include <hip/hip_bf16.h>

// LinMHA via full algebraic collapse:
//   M~_b = v_b^T k_b                  (512x512 per batch, bf16 MFMA, split-K=16)
//   P_b  = Wk @ M~_b^T
//   G_bh = SCALE^2 * P_bh @ Wv_h^T
//   Wc_b = Wq^T blockdiag(G_b) Wo^T
//   Out  = q @ Wc_b + b_o
// B=4, S=8192, C=512, H=8, DK=64.

typedef __attribute__((ext_vector_type(4))) float f32x4;
typedef __attribute__((ext_vector_type(8))) short short8;

#define DEVI __device__ __forceinline__

DEVI unsigned short f2bf(float f) {
  unsigned int u = __builtin_bit_cast(unsigned int, f);
  u += 0x7fffu + ((u >> 16) & 1u);   // RNE
  return (unsigned short)(u >> 16);
}
DEVI short8 pack8(f32x4 a, f32x4 b) {
  short8 r;
#pragma unroll
  for (int i = 0; i < 4; ++i) { r[i] = (short)f2bf(a[i]); r[i + 4] = (short)f2bf(b[i]); }
  return r;
}

// ---------------- K1: M~ partials = v^T k over s-chunks (bf16 MFMA) ----------------
// grid 1024: (b,split) pinned to one XCD (16 tiles of 128x128, 2MB k+v chunk in L2).
// LDS [c][s] pitch 40 shorts; writes are per-column 16B short8 granules with the
// granule index XOR-swizzled by (c>>2)&3 -> conflict-free writes AND reads (verified
// bank math: 8 lanes per 4-bank window on both sides).
__global__ __launch_bounds__(256, 3) void bigm_kernel(const float* __restrict__ kmat,
                                                      const float* __restrict__ vmat,
                                                      float* __restrict__ Mpart) {
  __shared__ __align__(16) unsigned short Vt[2][128 * 40];
  __shared__ __align__(16) unsigned short Kt[2][128 * 40];
  const int t = threadIdx.x;
  const int bid = blockIdx.x;
  const int xcd = bid & 7, jj = bid >> 3;      // jj 0..127
  const int p = ((jj >> 4) << 3) | xcd;        // 0..63 = b*16+split, XCD-pinned
  const int tile = jj & 15;
  const int b = p >> 4, split = p & 15;
  const int ti = tile >> 2, tj = tile & 3;
  const int cp0 = ti * 128, ck0 = tj * 128;    // c' tile (v-cols), c tile (k-cols)

  const int lane = t & 63, w = t >> 6;
  const int fr = lane & 15, fg = lane >> 4;
  const int wm = (w >> 1) * 64, wn = (w & 1) * 64;

  // staging: half = t>>7 (0:V, 1:K); u = t&127: cg = c-group (4 c), sg = s-group (8 s)
  const int half = t >> 7;
  const int u = t & 127;
  const int cg = u & 31, sg = u >> 5;
  const float* srcg = (half ? kmat : vmat)
                    + ((size_t)b * 8192 + (size_t)split * 512) * 512
                    + (half ? ck0 : cp0) + cg * 4;
  unsigned short* dstl = (half ? &Kt[0][0] : &Vt[0][0]);
  const int wbase = cg * 4 * 40 + ((sg ^ (cg & 3)) << 3);  // shorts

  f32x4 r[8];
  auto gload = [&](int sbase) {
    const float* pp = srcg + (size_t)(sbase + sg * 8) * 512;
#pragma unroll
    for (int j = 0; j < 8; ++j) r[j] = *(const f32x4*)(pp + j * 512);
  };
  auto lwrite = [&](int buf) {
    unsigned short* d = dstl + buf * (128 * 40) + wbase;
#pragma unroll
    for (int ci = 0; ci < 4; ++ci) {
      short8 wv;
#pragma unroll
      for (int j = 0; j < 8; ++j) wv[j] = (short)f2bf(r[j][ci]);
      *(short8*)(d + ci * 40) = wv;
    }
  };

  f32x4 acc[4][4] = {};

  gload(0);
  lwrite(0);
  __syncthreads();

  const int key = fr >> 2;  // read-side swizzle key = (row>>2)&3 (wm, i*16 are 0 mod 4)
  for (int step = 0; step < 16; ++step) {
    const int cur = step & 1;
    if (step < 15) gload((step + 1) * 32);
    short8 fa[4], fb[4];
#pragma unroll
    for (int i = 0; i < 4; ++i) {
      fa[i] = *(const short8*)&Vt[cur][(wm + i * 16 + fr) * 40 + ((fg ^ key) << 3)];
      fb[i] = *(const short8*)&Kt[cur][(wn + i * 16 + fr) * 40 + ((fg ^ key) << 3)];
    }
#pragma unroll
    for (int i = 0; i < 4; ++i)
#pragma unroll
      for (int j = 0; j < 4; ++j)
        acc[i][j] = __builtin_amdgcn_mfma_f32_16x16x32_bf16(fa[i], fb[j], acc[i][j], 0, 0, 0);
    if (step < 15) lwrite(cur ^ 1);
    __syncthreads();
  }
  // acc[i][j]: row = c' (A=Vt row), col = c (B=Kt row)
  float* gp = Mpart + (size_t)p * 262144;
#pragma unroll
  for (int i = 0; i < 4; ++i)
#pragma unroll
    for (int j = 0; j < 4; ++j)
#pragma unroll
      for (int r2 = 0; r2 < 4; ++r2)
        gp[(size_t)(cp0 + wm + i * 16 + fg * 4 + r2) * 512 + ck0 + wn + j * 16 + fr] = acc[i][j][r2];
}

// ---------------- K2: Msum = sum_splits Mpart -> bf16 [b][c'][c] ----------------
__global__ __launch_bounds__(256) void mred_kernel(const float* __restrict__ Mpart,
                                                   unsigned short* __restrict__ Msum) {
  const int idx = blockIdx.x * 256 + threadIdx.x;  // 1048576 total
  const int b = idx >> 18;
  const int r = idx & 262143;
  const float* src = Mpart + (size_t)(b * 16) * 262144 + r;
  float s = 0.f;
#pragma unroll
  for (int c = 0; c < 16; ++c) s += src[(size_t)c * 262144];
  Msum[idx] = f2bf(s);
}

// ---------------- K3: P_b[hd][c'] = sum_c Wk[hd][c] * Msum_b[c'][c] -> bf16 ----------------
__global__ __launch_bounds__(256, 3) void stepa_kernel(const float* __restrict__ Wk,
                                                       const unsigned short* __restrict__ Msum,
                                                       unsigned short* __restrict__ P) {
  __shared__ __align__(16) unsigned short Ab[2][128 * 40];
  __shared__ __align__(16) unsigned short Bb[2][128 * 40];
  const int t = threadIdx.x;
  const int n0 = blockIdx.x * 128;   // c'
  const int m0 = blockIdx.y * 128;   // hd
  const int b = blockIdx.z;
  const int lane = t & 63, w = t >> 6;
  const int wm = (w >> 1) * 64, wn = (w & 1) * 64;
  const int fr = lane & 15, fg = lane >> 4;
  const int sr = t >> 2;
  const int sk = (t & 3) * 8;

  const float* pAg = Wk + (size_t)(m0 + sr) * 512 + sk;
  const unsigned short* pBg = Msum + (size_t)b * 262144 + (size_t)(n0 + sr) * 512 + sk;

  f32x4 acc[4][4] = {};
  f32x4 a0, a1, a2, a3;
  short8 sb0, sb1;

  a0 = *(const f32x4*)(pAg);         a1 = *(const f32x4*)(pAg + 4);
  a2 = *(const f32x4*)(pAg + 32768); a3 = *(const f32x4*)(pAg + 32772);
  sb0 = *(const short8*)(pBg);
  sb1 = *(const short8*)(pBg + 32768);
  *(short8*)&Ab[0][sr * 40 + sk] = pack8(a0, a1);
  *(short8*)&Ab[0][(sr + 64) * 40 + sk] = pack8(a2, a3);
  *(short8*)&Bb[0][sr * 40 + sk] = sb0;
  *(short8*)&Bb[0][(sr + 64) * 40 + sk] = sb1;
  __syncthreads();

  for (int step = 0; step < 16; ++step) {
    const int cur = step & 1;
    if (step < 15) {
      const int k1 = (step + 1) * 32;
      a0 = *(const f32x4*)(pAg + k1);         a1 = *(const f32x4*)(pAg + k1 + 4);
      a2 = *(const f32x4*)(pAg + k1 + 32768); a3 = *(const f32x4*)(pAg + k1 + 32772);
      sb0 = *(const short8*)(pBg + k1);
      sb1 = *(const short8*)(pBg + k1 + 32768);
    }
    short8 afr[4], bfr[4];
#pragma unroll
    for (int i = 0; i < 4; ++i) {
      afr[i] = *(const short8*)&Ab[cur][(wm + i * 16 + fr) * 40 + fg * 8];
      bfr[i] = *(const short8*)&Bb[cur][(wn + i * 16 + fr) * 40 + fg * 8];
    }
#pragma unroll
    for (int i = 0; i < 4; ++i)
#pragma unroll
      for (int j = 0; j < 4; ++j)
        acc[i][j] = __builtin_amdgcn_mfma_f32_16x16x32_bf16(afr[i], bfr[j], acc[i][j], 0, 0, 0);
    if (step < 15) {
      const int nxt = cur ^ 1;
      *(short8*)&Ab[nxt][sr * 40 + sk] = pack8(a0, a1);
      *(short8*)&Ab[nxt][(sr + 64) * 40 + sk] = pack8(a2, a3);
      *(short8*)&Bb[nxt][sr * 40 + sk] = sb0;
      *(short8*)&Bb[nxt][(sr + 64) * 40 + sk] = sb1;
    }
    __syncthreads();
  }
#pragma unroll
  for (int i = 0; i < 4; ++i)
#pragma unroll
    for (int j = 0; j < 4; ++j)
#pragma unroll
      for (int r = 0; r < 4; ++r) {
        const int row = m0 + wm + i * 16 + fg * 4 + r;   // hd
        const int col = n0 + wn + j * 16 + fr;           // c'
        P[((size_t)b * 512 + row) * 512 + col] = f2bf(acc[i][j][r]);
      }
}

// ---------------- K4: G[b,h][d][e] = SCALE^2 * sum_c' P[hd][c'] Wv[he][c'] -> f32 ----------------
__global__ __launch_bounds__(64) void stepb_kernel(const unsigned short* __restrict__ P,
                                                   const float* __restrict__ Wv,
                                                   float* __restrict__ Gsum) {
  __shared__ __align__(16) unsigned short Ao[64 * 40];
  __shared__ __align__(16) unsigned short Bo[64 * 40];
  const int t = threadIdx.x;  // 0..63
  const int h = blockIdx.x;
  const int b = blockIdx.y;
  const int fr = t & 15, fg = t >> 4;
  f32x4 acc[4][4] = {};
  for (int step = 0; step < 16; ++step) {
    const int k0 = step * 32;
    const unsigned short* pa = P + ((size_t)b * 512 + h * 64 + t) * 512 + k0;
#pragma unroll
    for (int i = 0; i < 4; ++i) *(short8*)&Ao[t * 40 + i * 8] = *(const short8*)(pa + i * 8);
    const float* pb = Wv + (size_t)(h * 64 + t) * 512 + k0;
#pragma unroll
    for (int i = 0; i < 4; ++i) {
      f32x4 x0 = *(const f32x4*)(pb + i * 8);
      f32x4 x1 = *(const f32x4*)(pb + i * 8 + 4);
      *(short8*)&Bo[t * 40 + i * 8] = pack8(x0, x1);
    }
    __syncthreads();
    short8 afr[4], bfr[4];
#pragma unroll
    for (int i = 0; i < 4; ++i) {
      afr[i] = *(const short8*)&Ao[(i * 16 + fr) * 40 + fg * 8];
      bfr[i] = *(const short8*)&Bo[(i * 16 + fr) * 40 + fg * 8];
    }
#pragma unroll
    for (int i = 0; i < 4; ++i)
#pragma unroll
      for (int j = 0; j < 4; ++j)
        acc[i][j] = __builtin_amdgcn_mfma_f32_16x16x32_bf16(afr[i], bfr[j], acc[i][j], 0, 0, 0);
    __syncthreads();
  }
  float* gout = Gsum + (size_t)(b * 8 + h) * 4096;
#pragma unroll
  for (int i = 0; i < 4; ++i)
#pragma unroll
    for (int j = 0; j < 4; ++j)
#pragma unroll
      for (int r = 0; r < 4; ++r)
        gout[(i * 16 + fg * 4 + r) * 64 + (j * 16 + fr)] = acc[i][j][r] * 0.015625f;  // SCALE^2
}

// ---------------- K5: T3[b][c][h*64+e] = sum_d Wq[h*64+d][c] * G[b,h,d,e] -> bf16 ----------------
__global__ __launch_bounds__(256) void t3_kernel(const float* __restrict__ Wq,
                                                 const float* __restrict__ Gsum,
                                                 unsigned short* __restrict__ T3) {
  __shared__ float Wl[64][64];
  __shared__ float Gl[64][64];
  const int t = threadIdx.x;
  const int c0 = blockIdx.x * 64;
  const int h = blockIdx.y;
  const int b = blockIdx.z;
  const int dd = t >> 2;
  const int c4 = (t & 3) * 16;
  const float* wp = Wq + (size_t)(h * 64 + dd) * 512 + c0 + c4;
  const float* gp = Gsum + (size_t)(b * 8 + h) * 4096 + dd * 64 + c4;
#pragma unroll
  for (int i = 0; i < 4; ++i) {
    *(f32x4*)&Wl[dd][c4 + i * 4] = *(const f32x4*)(wp + i * 4);
    *(f32x4*)&Gl[dd][c4 + i * 4] = *(const f32x4*)(gp + i * 4);
  }
  __syncthreads();
  const int cl0 = (t >> 4) * 4;
  const int e0 = (t & 15) * 4;
  float acc[4][4] = {};
  for (int d = 0; d < 64; ++d) {
    f32x4 wv = *(const f32x4*)&Wl[d][cl0];
    f32x4 gv = *(const f32x4*)&Gl[d][e0];
#pragma unroll
    for (int i = 0; i < 4; ++i)
#pragma unroll
      for (int j = 0; j < 4; ++j)
        acc[i][j] += wv[i] * gv[j];
  }
#pragma unroll
  for (int i = 0; i < 4; ++i)
#pragma unroll
    for (int j = 0; j < 4; ++j)
      T3[((size_t)b * 512 + c0 + cl0 + i) * 512 + h * 64 + e0 + j] = f2bf(acc[i][j]);
}

// ---------------- K6: WcT[b][n][c] = sum_j Wo[n][j] * T3[b][c][j] -> bf16 ----------------
__global__ __launch_bounds__(64) void wc_kernel(const float* __restrict__ Wo,
                                                const unsigned short* __restrict__ T3,
                                                unsigned short* __restrict__ WcT) {
  __shared__ __align__(16) unsigned short Ao[64 * 48];
  __shared__ __align__(16) unsigned short Bo[64 * 48];
  const int t = threadIdx.x;  // 0..63
  const int n0 = blockIdx.x * 64;
  const int c0 = blockIdx.y * 64;
  const int b = blockIdx.z;
  const int fr = t & 15, fg = t >> 4;
  f32x4 acc[4][4] = {};
  for (int step = 0; step < 16; ++step) {
    const int k0 = step * 32;
    const float* pa = Wo + (size_t)(n0 + t) * 512 + k0;
    unsigned short tmp[32];
#pragma unroll
    for (int i = 0; i < 8; ++i) {
      f32x4 vv = *(const f32x4*)(pa + i * 4);
#pragma unroll
      for (int j = 0; j < 4; ++j) tmp[i * 4 + j] = f2bf(vv[j]);
    }
#pragma unroll
    for (int i = 0; i < 4; ++i) *(short8*)&Ao[t * 48 + i * 8] = *(const short8*)&tmp[i * 8];
    const unsigned short* pb = T3 + ((size_t)b * 512 + c0 + t) * 512 + k0;
#pragma unroll
    for (int i = 0; i < 4; ++i) *(short8*)&Bo[t * 48 + i * 8] = *(const short8*)(pb + i * 8);
    __syncthreads();
    short8 afr[4], bfr[4];
#pragma unroll
    for (int i = 0; i < 4; ++i) {
      afr[i] = *(const short8*)&Ao[(i * 16 + fr) * 48 + fg * 8];
      bfr[i] = *(const short8*)&Bo[(i * 16 + fr) * 48 + fg * 8];
    }
#pragma unroll
    for (int i = 0; i < 4; ++i)
#pragma unroll
      for (int j = 0; j < 4; ++j)
        acc[i][j] = __builtin_amdgcn_mfma_f32_16x16x32_bf16(afr[i], bfr[j], acc[i][j], 0, 0, 0);
    __syncthreads();
  }
#pragma unroll
  for (int i = 0; i < 4; ++i)
#pragma unroll
    for (int j = 0; j < 4; ++j)
#pragma unroll
      for (int r = 0; r < 4; ++r)
        WcT[((size_t)b * 512 + n0 + i * 16 + fg * 4 + r) * 512 + c0 + j * 16 + fr] =
            f2bf(acc[i][j][r]);
}

// ---------------- K7: Out = q @ Wc[b] + b_o -> f32 (2-phase, XCD-grouped) ----------------
__global__ __launch_bounds__(256, 4) void out_kernel(const float* __restrict__ q,
                                                     const unsigned short* __restrict__ WcT,
                                                     const float* __restrict__ bo,
                                                     float* __restrict__ Out) {
  __shared__ __align__(16) unsigned short Ab[2][128 * 40];
  __shared__ __align__(16) unsigned short Bb[2][128 * 40];
  const int t = threadIdx.x;
  const int bid = blockIdx.x;
  const int xcd = bid & 7, idx = bid >> 3;
  const int mt = xcd * 32 + (idx >> 2);
  const int nt = idx & 3;
  const int m0 = mt * 128, n0 = nt * 128;
  const unsigned short* Wc = WcT + ((size_t)(m0 >> 13)) * 512 * 512;  // batch = m0/8192
  const int lane = t & 63, w = t >> 6;
  const int wm = (w >> 1) * 64, wn = (w & 1) * 64;
  const int fr = lane & 15, fg = lane >> 4;
  const int sr = t >> 2;
  const int sk = (t & 3) * 8;

  const float* pAg = q + (size_t)(m0 + sr) * 512 + sk;
  const unsigned short* pBg = Wc + (size_t)(n0 + sr) * 512 + sk;

  f32x4 acc[4][4] = {};
  f32x4 a0, a1, a2, a3;
  short8 sb0, sb1;

  a0 = *(const f32x4*)(pAg);         a1 = *(const f32x4*)(pAg + 4);
  a2 = *(const f32x4*)(pAg + 32768); a3 = *(const f32x4*)(pAg + 32772);
  sb0 = *(const short8*)(pBg);
  sb1 = *(const short8*)(pBg + 32768);
  *(short8*)&Ab[0][sr * 40 + sk] = pack8(a0, a1);
  *(short8*)&Ab[0][(sr + 64) * 40 + sk] = pack8(a2, a3);
  *(short8*)&Bb[0][sr * 40 + sk] = sb0;
  *(short8*)&Bb[0][(sr + 64) * 40 + sk] = sb1;
  __syncthreads();

  for (int step = 0; step < 16; ++step) {
    const int cur = step & 1;
    if (step < 15) {
      const int k1 = (step + 1) * 32;
      a0 = *(const f32x4*)(pAg + k1);         a1 = *(const f32x4*)(pAg + k1 + 4);
      a2 = *(const f32x4*)(pAg + k1 + 32768); a3 = *(const f32x4*)(pAg + k1 + 32772);
      sb0 = *(const short8*)(pBg + k1);
      sb1 = *(const short8*)(pBg + k1 + 32768);
    }
    short8 afr[4], bfr[4];
#pragma unroll
    for (int i = 0; i < 4; ++i) {
      afr[i] = *(const short8*)&Ab[cur][(wm + i * 16 + fr) * 40 + fg * 8];
      bfr[i] = *(const short8*)&Bb[cur][(wn + i * 16 + fr) * 40 + fg * 8];
    }
#pragma unroll
    for (int i = 0; i < 4; ++i)
#pragma unroll
      for (int j = 0; j < 4; ++j)
        acc[i][j] = __builtin_amdgcn_mfma_f32_16x16x32_bf16(afr[i], bfr[j], acc[i][j], 0, 0, 0);
    if (step < 15) {
      const int nxt = cur ^ 1;
      *(short8*)&Ab[nxt][sr * 40 + sk] = pack8(a0, a1);
      *(short8*)&Ab[nxt][(sr + 64) * 40 + sk] = pack8(a2, a3);
      *(short8*)&Bb[nxt][sr * 40 + sk] = sb0;
      *(short8*)&Bb[nxt][(sr + 64) * 40 + sk] = sb1;
    }
    __syncthreads();
  }
  float bias[4];
#pragma unroll
  for (int j = 0; j < 4; ++j) bias[j] = bo[n0 + wn + j * 16 + fr];
#pragma unroll
  for (int i = 0; i < 4; ++i)
#pragma unroll
    for (int j = 0; j < 4; ++j)
#pragma unroll
      for (int r = 0; r < 4; ++r) {
        const int row = m0 + wm + i * 16 + fg * 4 + r;
        const int col = n0 + wn + j * 16 + fr;
        Out[(size_t)row * 512 + col] = acc[i][j][r] + bias[j];
      }
}

extern "C" void kernel_launch(void* const* d_in, const int* in_sizes, int n_in,
                              void* d_out, int out_size, void* d_ws, size_t ws_size,
                              hipStream_t stream) {
  const float* q  = (const float*)d_in[0];
  const float* k  = (const float*)d_in[1];
  const float* v  = (const float*)d_in[2];
  const float* Wq = (const float*)d_in[3];
  const float* Wk = (const float*)d_in[4];
  const float* Wv = (const float*)d_in[5];
  const float* Wo = (const float*)d_in[6];
  const float* bo = (const float*)d_in[7];
  float* Out = (float*)d_out;

  // Mpart (64 MB f32, 64 partials of 1MB) fills d_out exactly until out_kernel overwrites it.
  float* Mpart = (float*)d_out;
  char* ws = (char*)d_ws;
  unsigned short* Msum = (unsigned short*)ws;                          // 2 MB
  unsigned short* P    = (unsigned short*)(ws + (size_t)2 * 1048576);  // 2 MB
  float* Gsum          = (float*)(ws + (size_t)4 * 1048576);           // 0.5 MB
  unsigned short* T3   = (unsigned short*)(ws + (size_t)5 * 1048576);  // 2 MB
  unsigned short* WcT  = (unsigned short*)(ws + (size_t)7 * 1048576);  // 2 MB

  bigm_kernel<<<1024, 256, 0, stream>>>(k, v, Mpart);
  mred_kernel<<<4096, 256, 0, stream>>>(Mpart, Msum);
  stepa_kernel<<<dim3(4, 4, 4), 256, 0, stream>>>(Wk, Msum, P);
  stepb_kernel<<<dim3(8, 4), 64, 0, stream>>>(P, Wv, Gsum);
  t3_kernel<<<dim3(8, 8, 4), 256, 0, stream>>>(Wq, Gsum, T3);
  wc_kernel<<<dim3(8, 8, 4), 64, 0, stream>>>(Wo, T3, WcT);
  out_kernel<<<1024, 256, 0, stream>>>(q, WcT, bo, Out);
}